// Round 4
// baseline (135.401 us; speedup 1.0000x reference)
//
#include <hip/hip_runtime.h>

#define SMOOTH_F 1e-7f

typedef float f32x4 __attribute__((ext_vector_type(4)));

constexpr int B = 8, C = 12, S = 4, H = 512, W = 512;
constexpr int HW    = H * W;          // 262144 = 2^18
constexpr int NPIX  = B * HW;         // 2097152
constexpr int QUADS = NPIX / 4;       // 524288
constexpr int BLOCK = 256;
constexpr int GRID  = QUADS / BLOCK;  // 2048 -> 8 blocks/CU, 1 quad/thread

// sums layout in d_ws (floats):
// [0..3]   interS   [4..7]  isumS   [8..11]  tsumS
// [12..23] interC   [24..35] isumC  [36..47] tsumC
constexpr int NSUMS = 48;

__global__ __launch_bounds__(BLOCK, 8) void fused_kernel(
    const float* __restrict__ ss,   // [B,S,H,W]
    const float* __restrict__ cs,   // [B,C,H,W]
    const int*   __restrict__ tgt,  // [B,H,W]
    const int*   __restrict__ s2s,  // [C]
    float* __restrict__ out_fc,     // [B,C,H,W]  (d_out+1)   4B-aligned only
    float* __restrict__ out_oh,     // [B,C,H,W]  (d_out+1+N) 4B-aligned only
    float* __restrict__ sums)       // [48]
{
    const int q   = blockIdx.x * BLOCK + threadIdx.x; // quad index
    const int p   = q << 2;
    const int b   = p >> 18;          // p / HW
    const int rem = p & (HW - 1);

    float interS[S], isumS[S];
    float interC[C], isumC[C];
    int   tS[S];   // wave-uniform (ballot-derived)
    int   tC[C];

    // ---- targets + super-targets ----
    const int4 t4 = *reinterpret_cast<const int4*>(tgt + p);
    const int t[4] = {t4.x, t4.y, t4.z, t4.w};
    int st[4];
    #pragma unroll
    for (int i = 0; i < 4; i++) st[i] = s2s[t[i]];

    // ---- superclass channels: cache + accumulate ----
    float ssv[S][4];
    #pragma unroll
    for (int s = 0; s < S; s++) {
        const float4 v = *reinterpret_cast<const float4*>(ss + (b * S + s) * HW + rem);
        ssv[s][0] = v.x; ssv[s][1] = v.y; ssv[s][2] = v.z; ssv[s][3] = v.w;
        isumS[s] = v.x + v.y + v.z + v.w;
        interS[s] = 0.f; tS[s] = 0;
        #pragma unroll
        for (int i = 0; i < 4; i++) {
            const bool m = (st[i] == s);
            interS[s] += m ? ssv[s][i] : 0.f;
            tS[s] += (int)__popcll(__ballot(m));   // wave-uniform count
        }
    }

    // ---- class channels: batched loads ----
    float cv[C][4];
    #pragma unroll
    for (int c = 0; c < C; c++) {
        const float4 v = *reinterpret_cast<const float4*>(cs + (b * C + c) * HW + rem);
        cv[c][0] = v.x; cv[c][1] = v.y; cv[c][2] = v.z; cv[c][3] = v.w;
    }

    // ---- process + vectorized stores (plain stores: L2 merges the
    // 4B-misaligned 16B writes into full lines; NT caused HBM RMW) ----
    #pragma unroll
    for (int c = 0; c < C; c++) {
        const int base = (b * C + c) * HW + rem;
        const int sup  = s2s[c];   // uniform -> scalar load
        isumC[c] = cv[c][0] + cv[c][1] + cv[c][2] + cv[c][3];
        interC[c] = 0.f; tC[c] = 0;
        f32x4 oh4, fc4;
        #pragma unroll
        for (int i = 0; i < 4; i++) {
            const bool eq = (t[i] == c);
            const float sv = (sup == 0) ? ssv[0][i]
                           : (sup == 1) ? ssv[1][i]
                           : (sup == 2) ? ssv[2][i]
                           :              ssv[3][i];
            oh4[i] = eq ? 1.f : 0.f;
            fc4[i] = cv[c][i] * sv;
            interC[c] += eq ? cv[c][i] : 0.f;
            tC[c] += (int)__popcll(__ballot(eq));
        }
        *reinterpret_cast<f32x4*>(out_oh + base) = oh4;
        *reinterpret_cast<f32x4*>(out_fc + base) = fc4;
    }

    // ---- block reduction: 32 float partials + 16 uniform counts ----
    float vals[32];
    #pragma unroll
    for (int s = 0; s < S; s++) { vals[s] = interS[s]; vals[4 + s] = isumS[s]; }
    #pragma unroll
    for (int c = 0; c < C; c++) { vals[8 + c] = interC[c]; vals[20 + c] = isumC[c]; }

    __shared__ float red[BLOCK / 64][NSUMS];
    const int lane = threadIdx.x & 63;
    const int wv   = threadIdx.x >> 6;

    #pragma unroll
    for (int k = 0; k < 32; k++) {
        float v = vals[k];
        #pragma unroll
        for (int o = 32; o > 0; o >>= 1) v += __shfl_xor(v, o, 64);
        if (lane == 0) {
            const int idx = (k < 8) ? k : (k < 20) ? (12 + (k - 8)) : (24 + (k - 20));
            red[wv][idx] = v;
        }
    }
    if (lane == 0) {
        #pragma unroll
        for (int s = 0; s < S; s++) red[wv][8 + s]  = (float)tS[s];
        #pragma unroll
        for (int c = 0; c < C; c++) red[wv][36 + c] = (float)tC[c];
    }
    __syncthreads();
    if (threadIdx.x < NSUMS) {
        const float sblk = red[0][threadIdx.x] + red[1][threadIdx.x]
                         + red[2][threadIdx.x] + red[3][threadIdx.x];
        atomicAdd(&sums[threadIdx.x], sblk);
    }
}

__global__ void loss_kernel(const float* __restrict__ sums,
                            const float* __restrict__ w,
                            float* __restrict__ out)
{
    if (threadIdx.x == 0 && blockIdx.x == 0) {
        float superL = 0.f;
        #pragma unroll
        for (int s = 0; s < S; s++)
            superL += 1.f - (2.f * sums[s] + SMOOTH_F) / (sums[4 + s] + sums[8 + s] + SMOOTH_F);
        float finalL = 0.f, wsum = 0.f;
        #pragma unroll
        for (int c = 0; c < C; c++) {
            wsum   += w[c];
            finalL += w[c] * (1.f - (2.f * sums[12 + c] + SMOOTH_F) / (sums[24 + c] + sums[36 + c] + SMOOTH_F));
        }
        out[0] = 0.1f * superL / (float)S + finalL / wsum;
    }
}

extern "C" void kernel_launch(void* const* d_in, const int* in_sizes, int n_in,
                              void* d_out, int out_size, void* d_ws, size_t ws_size,
                              hipStream_t stream) {
    const float* ss  = (const float*)d_in[0]; // superclass_scores [B,S,H,W]
    const float* cs  = (const float*)d_in[1]; // class_score       [B,C,H,W]
    const float* w   = (const float*)d_in[2]; // weights [C]
    const int*   tgt = (const int*)d_in[3];   // target [B,H,W]
    const int*   s2s = (const int*)d_in[4];   // sub2super [C]

    float* out    = (float*)d_out;
    float* out_fc = out + 1;                          // final_class_score
    float* out_oh = out + 1 + (size_t)B * C * HW;     // target_one_hot
    float* sums   = (float*)d_ws;

    hipMemsetAsync(sums, 0, NSUMS * sizeof(float), stream);
    fused_kernel<<<GRID, BLOCK, 0, stream>>>(ss, cs, tgt, s2s, out_fc, out_oh, sums);
    loss_kernel<<<1, 64, 0, stream>>>(sums, w, out);
}

// Round 5
// 88.414 us; speedup vs baseline: 1.5314x; 1.5314x over previous
//
#include <hip/hip_runtime.h>

#define SMOOTH_F 1e-7f

typedef float f32x4 __attribute__((ext_vector_type(4)));
typedef float f32x2 __attribute__((ext_vector_type(2)));

constexpr int B = 8, C = 12, S = 4, H = 512, W = 512;
constexpr int HW    = H * W;          // 262144 = 2^18
constexpr int NPIX  = B * HW;         // 2097152
constexpr int QUADS = NPIX / 4;       // 524288
constexpr int BLOCK = 256;
constexpr int GRID  = QUADS / BLOCK;  // 2048, 1 quad/thread
constexpr int N     = B * C * HW;     // fc / oh element count

// sums layout in d_ws (floats):
// [0..3]   interS   [4..7]  isumS   [8..11]  tsumS
// [12..23] interC   [24..35] isumC  [36..47] tsumC
constexpr int NSUMS = 48;

__global__ __launch_bounds__(BLOCK, 4) void fused_kernel(
    const float* __restrict__ ss,   // [B,S,H,W]
    const float* __restrict__ cs,   // [B,C,H,W]
    const int*   __restrict__ tgt,  // [B,H,W]
    const int*   __restrict__ s2s,  // [C]
    float* __restrict__ outp,       // raw d_out: [loss, fc(N), oh(N)]
    float* __restrict__ sums)       // [48]
{
    const int q   = blockIdx.x * BLOCK + threadIdx.x; // quad index
    const int p   = q << 2;
    const int b   = p >> 18;          // p / HW
    const int rem = p & (HW - 1);
    const int lane = threadIdx.x & 63;
    const int wv   = threadIdx.x >> 6;

    // ---- targets + super-targets ----
    const int4 t4 = *reinterpret_cast<const int4*>(tgt + p);
    const int t[4] = {t4.x, t4.y, t4.z, t4.w};
    int st[4];
    #pragma unroll
    for (int i = 0; i < 4; i++) st[i] = s2s[t[i]];

    // ---- superclass channels: cache + accumulate ----
    float interS[S], isumS[S];
    int   tS[S], tC[C];
    float ssv[S][4];
    #pragma unroll
    for (int s = 0; s < S; s++) {
        const float4 v = *reinterpret_cast<const float4*>(ss + (b * S + s) * HW + rem);
        ssv[s][0] = v.x; ssv[s][1] = v.y; ssv[s][2] = v.z; ssv[s][3] = v.w;
        isumS[s] = v.x + v.y + v.z + v.w;
        interS[s] = 0.f; tS[s] = 0;
        #pragma unroll
        for (int i = 0; i < 4; i++) {
            const bool m = (st[i] == s);
            interS[s] += m ? ssv[s][i] : 0.f;
            tS[s] += (int)__popcll(__ballot(m));
        }
    }

    // ---- class channels: batched loads ----
    float cv[C][4];
    #pragma unroll
    for (int c = 0; c < C; c++) {
        const float4 v = *reinterpret_cast<const float4*>(cs + (b * C + c) * HW + rem);
        cv[c][0] = v.x; cv[c][1] = v.y; cv[c][2] = v.z; cv[c][3] = v.w;
    }

    // ---- phase A: wave-edge values (lane63's fc3/oh3) into LDS ----
    __shared__ float edge[BLOCK / 64][C][2];
    if (lane == 63) {
        #pragma unroll
        for (int c = 0; c < C; c++) {
            const int sup = s2s[c];
            const float sv3 = (sup == 0) ? ssv[0][3]
                            : (sup == 1) ? ssv[1][3]
                            : (sup == 2) ? ssv[2][3]
                            :              ssv[3][3];
            edge[wv][c][0] = cv[c][3] * sv3;
            edge[wv][c][1] = (t[3] == c) ? 1.f : 0.f;
        }
    }
    __syncthreads();

    // ---- phase C: per-channel compute + aligned NT stores ----
    float interC[C], isumC[C];
    #pragma unroll
    for (int c = 0; c < C; c++) {
        const int J   = (b * C + c) * HW + rem;   // fc flat index, J%4==0
        const int sup = s2s[c];
        isumC[c] = cv[c][0] + cv[c][1] + cv[c][2] + cv[c][3];
        interC[c] = 0.f; tC[c] = 0;
        float fc[4], oh[4];
        #pragma unroll
        for (int i = 0; i < 4; i++) {
            const bool eq = (t[i] == c);
            const float sv = (sup == 0) ? ssv[0][i]
                           : (sup == 1) ? ssv[1][i]
                           : (sup == 2) ? ssv[2][i]
                           :              ssv[3][i];
            oh[i] = eq ? 1.f : 0.f;
            fc[i] = cv[c][i] * sv;
            interC[c] += eq ? cv[c][i] : 0.f;
            tC[c] += (int)__popcll(__ballot(eq));
        }
        // shifted window: OUT[J + k] = fc[J-1+k], aligned 16B
        float pfc = __shfl_up(fc[3], 1);
        float poh = __shfl_up(oh[3], 1);
        if (lane == 0 && wv > 0) { pfc = edge[wv - 1][c][0]; poh = edge[wv - 1][c][1]; }

        if (threadIdx.x != 0) {
            const f32x4 vfc = {pfc, fc[0], fc[1], fc[2]};
            const f32x4 voh = {poh, oh[0], oh[1], oh[2]};
            __builtin_nontemporal_store(vfc, reinterpret_cast<f32x4*>(outp + J));
            __builtin_nontemporal_store(voh, reinterpret_cast<f32x4*>(outp + N + J));
        } else {
            // first thread of block: 3 leading elements, scalar path
            __builtin_nontemporal_store(fc[0], outp + J + 1);
            const f32x2 vfc2 = {fc[1], fc[2]};
            __builtin_nontemporal_store(vfc2, reinterpret_cast<f32x2*>(outp + J + 2));
            __builtin_nontemporal_store(oh[0], outp + N + J + 1);
            const f32x2 voh2 = {oh[1], oh[2]};
            __builtin_nontemporal_store(voh2, reinterpret_cast<f32x2*>(outp + N + J + 2));
        }
        if (threadIdx.x == BLOCK - 1) {
            // trailing element -> first slot of next block's window
            __builtin_nontemporal_store(fc[3], outp + J + 4);
            __builtin_nontemporal_store(oh[3], outp + N + J + 4);
        }
    }

    // ---- block reduction: 32 float partials + 16 uniform counts ----
    float vals[32];
    #pragma unroll
    for (int s = 0; s < S; s++) { vals[s] = interS[s]; vals[4 + s] = isumS[s]; }
    #pragma unroll
    for (int c = 0; c < C; c++) { vals[8 + c] = interC[c]; vals[20 + c] = isumC[c]; }

    __shared__ float red[BLOCK / 64][NSUMS];
    #pragma unroll
    for (int k = 0; k < 32; k++) {
        float v = vals[k];
        #pragma unroll
        for (int o = 32; o > 0; o >>= 1) v += __shfl_xor(v, o, 64);
        if (lane == 0) {
            const int idx = (k < 8) ? k : (k < 20) ? (12 + (k - 8)) : (24 + (k - 20));
            red[wv][idx] = v;
        }
    }
    if (lane == 0) {
        #pragma unroll
        for (int s = 0; s < S; s++) red[wv][8 + s]  = (float)tS[s];
        #pragma unroll
        for (int c = 0; c < C; c++) red[wv][36 + c] = (float)tC[c];
    }
    __syncthreads();
    if (threadIdx.x < NSUMS) {
        const float sblk = red[0][threadIdx.x] + red[1][threadIdx.x]
                         + red[2][threadIdx.x] + red[3][threadIdx.x];
        atomicAdd(&sums[threadIdx.x], sblk);
    }
}

__global__ void loss_kernel(const float* __restrict__ sums,
                            const float* __restrict__ w,
                            float* __restrict__ out)
{
    if (threadIdx.x == 0 && blockIdx.x == 0) {
        float superL = 0.f;
        #pragma unroll
        for (int s = 0; s < S; s++)
            superL += 1.f - (2.f * sums[s] + SMOOTH_F) / (sums[4 + s] + sums[8 + s] + SMOOTH_F);
        float finalL = 0.f, wsum = 0.f;
        #pragma unroll
        for (int c = 0; c < C; c++) {
            wsum   += w[c];
            finalL += w[c] * (1.f - (2.f * sums[12 + c] + SMOOTH_F) / (sums[24 + c] + sums[36 + c] + SMOOTH_F));
        }
        out[0] = 0.1f * superL / (float)S + finalL / wsum;
    }
}

extern "C" void kernel_launch(void* const* d_in, const int* in_sizes, int n_in,
                              void* d_out, int out_size, void* d_ws, size_t ws_size,
                              hipStream_t stream) {
    const float* ss  = (const float*)d_in[0]; // superclass_scores [B,S,H,W]
    const float* cs  = (const float*)d_in[1]; // class_score       [B,C,H,W]
    const float* w   = (const float*)d_in[2]; // weights [C]
    const int*   tgt = (const int*)d_in[3];   // target [B,H,W]
    const int*   s2s = (const int*)d_in[4];   // sub2super [C]

    float* outp = (float*)d_out;
    float* sums = (float*)d_ws;

    (void)hipMemsetAsync(sums, 0, NSUMS * sizeof(float), stream);
    fused_kernel<<<GRID, BLOCK, 0, stream>>>(ss, cs, tgt, s2s, outp, sums);
    loss_kernel<<<1, 64, 0, stream>>>(sums, w, outp);
}